// Round 3
// baseline (1386.296 us; speedup 1.0000x reference)
//
#include <hip/hip_runtime.h>
#include <hip/hip_cooperative_groups.h>
#include <math.h>

namespace cg = cooperative_groups;

#define HID 150
#define EMB 300
#define NOUT 5
#define NNODES 8191
#define NLEAF 4096
#define LEAF_START 4095
#define HSTR 152            // padded H/C row stride (608 B)
#define WCOLS3 600          // leaf weights: [k][4h+g], g:0=i,1=o,2=u,3=pad
#define UCOLS3 1200         // level weights: [k][8h+g], g:0=i,1=fl,2=fr,3=o,4=u,5..7=pad
#define BLK 192
#define MAXG 512

struct P {
    const float *Wi, *bi, *Wo, *bo, *Wu, *bu;
    const float *U0i, *U1i, *bbi;
    const float *U00f, *U01f, *U10f, *U11f, *bbf;
    const float *U0o, *U1o, *bbo;
    const float *U0u, *U1u, *bbu;
    const float *Why, *by, *emb;
    const int *scores, *words, *lchs, *rchs;
    float *Wt3, *Ut3, *H, *C, *partials, *out;
};

__device__ __forceinline__ float sigmoidf_(float x) { return 1.0f / (1.0f + __expf(-x)); }

// ---- leaf tile: 8 leaves, thread h owns gates i,o,u for its h ----
__device__ void leaf_tile(const P& p, int t, float* Xs, int* sw)
{
    const int tid = threadIdx.x;
    const int leaf0 = LEAF_START + t * 8;
    if (tid < 8) sw[tid] = p.words[leaf0 + tid];
    __syncthreads();
    for (int m = 0; m < 8; ++m) {
        const float* src = p.emb + (long)sw[m] * EMB;
        for (int e = tid; e < EMB; e += BLK) Xs[e * 8 + m] = src[e];
    }
    __syncthreads();

    const int h = tid;
    if (h < HID) {
        float a0[8], a1[8], a2[8];
#pragma unroll
        for (int m = 0; m < 8; ++m) { a0[m] = 0.f; a1[m] = 0.f; a2[m] = 0.f; }
        const float* wp = p.Wt3 + 4 * h;
#pragma unroll 4
        for (int k = 0; k < EMB; ++k) {
            float4 w = *(const float4*)(wp + (long)k * WCOLS3);
            float4 xa = *(const float4*)&Xs[k * 8];
            float4 xb = *(const float4*)&Xs[k * 8 + 4];
            float xv[8] = {xa.x, xa.y, xa.z, xa.w, xb.x, xb.y, xb.z, xb.w};
#pragma unroll
            for (int m = 0; m < 8; ++m) {
                a0[m] = fmaf(xv[m], w.x, a0[m]);
                a1[m] = fmaf(xv[m], w.y, a1[m]);
                a2[m] = fmaf(xv[m], w.z, a2[m]);
            }
        }
        float bI = p.bi[h], bO = p.bo[h], bU = p.bu[h];
#pragma unroll
        for (int m = 0; m < 8; ++m) {
            float ig = sigmoidf_(a0[m] + bI);
            float og = sigmoidf_(a1[m] + bO);
            float uv = tanhf(a2[m] + bU);
            float c  = ig * uv;
            float hh = og * tanhf(c);
            long node = leaf0 + m;
            p.H[node * HSTR + h] = hh;
            p.C[node * HSTR + h] = c;
        }
    }
    __syncthreads();
}

// ---- internal level pass: NB nodes/tile, CSn-way h-range split ----
template<int NB, int CSn>
__device__ void level_pass(const P& p, int d, float* Xs, int* sl, int* sr)
{
    const int s = (1 << d) - 1, count = 1 << d;
    const int nodeTiles = count / NB;
    const int tiles = nodeTiles * CSn;
    const int tid = threadIdx.x;

    for (int t = blockIdx.x; t < tiles; t += gridDim.x) {
        const int nt = t / CSn, cs = t - nt * CSn;
        const int node0 = s + nt * NB;

        if (tid < NB) { sl[tid] = p.lchs[node0 + tid]; sr[tid] = p.rchs[node0 + tid]; }
        __syncthreads();
        for (int m = 0; m < NB; ++m) {
            const float* hl = p.H + (long)sl[m] * HSTR;
            const float* hr = p.H + (long)sr[m] * HSTR;
            for (int e = tid; e < EMB; e += BLK)
                Xs[e * 8 + m] = (e < HID) ? hl[e] : hr[e - HID];
        }
        __syncthreads();

        const int hbeg = (cs * HID) / CSn, hend = ((cs + 1) * HID) / CSn;
        const int h = hbeg + tid;
        if (h < hend) {
            float acc[NB][5];
#pragma unroll
            for (int m = 0; m < NB; ++m)
#pragma unroll
                for (int g = 0; g < 5; ++g) acc[m][g] = 0.f;

            const float* wp = p.Ut3 + 8 * h;
            if constexpr (NB <= 2) {
#pragma unroll 8
                for (int k = 0; k < EMB; ++k) {
                    const float* wr = wp + (long)k * UCOLS3;
                    float4 w4 = *(const float4*)wr;
                    float  w5 = wr[4];
#pragma unroll
                    for (int m = 0; m < NB; ++m) {
                        float x = Xs[k * 8 + m];
                        acc[m][0] = fmaf(x, w4.x, acc[m][0]);
                        acc[m][1] = fmaf(x, w4.y, acc[m][1]);
                        acc[m][2] = fmaf(x, w4.z, acc[m][2]);
                        acc[m][3] = fmaf(x, w4.w, acc[m][3]);
                        acc[m][4] = fmaf(x, w5,   acc[m][4]);
                    }
                }
            } else {
#pragma unroll 4
                for (int k = 0; k < EMB; ++k) {
                    const float* wr = wp + (long)k * UCOLS3;
                    float4 w4 = *(const float4*)wr;
                    float  w5 = wr[4];
                    float xv[NB];
                    if constexpr (NB == 8) {
                        float4 xa = *(const float4*)&Xs[k * 8];
                        float4 xb = *(const float4*)&Xs[k * 8 + 4];
                        xv[0]=xa.x; xv[1]=xa.y; xv[2]=xa.z; xv[3]=xa.w;
                        xv[4]=xb.x; xv[5]=xb.y; xv[6]=xb.z; xv[7]=xb.w;
                    } else {
                        float4 xa = *(const float4*)&Xs[k * 8];
                        xv[0]=xa.x; xv[1]=xa.y;
                        if constexpr (NB == 4) { xv[2]=xa.z; xv[3]=xa.w; }
                    }
#pragma unroll
                    for (int m = 0; m < NB; ++m) {
                        acc[m][0] = fmaf(xv[m], w4.x, acc[m][0]);
                        acc[m][1] = fmaf(xv[m], w4.y, acc[m][1]);
                        acc[m][2] = fmaf(xv[m], w4.z, acc[m][2]);
                        acc[m][3] = fmaf(xv[m], w4.w, acc[m][3]);
                        acc[m][4] = fmaf(xv[m], w5,   acc[m][4]);
                    }
                }
            }

            float bI = p.bbi[h], bF = p.bbf[h], bO = p.bbo[h], bU = p.bbu[h];
#pragma unroll
            for (int m = 0; m < NB; ++m) {
                float ig = sigmoidf_(acc[m][0] + bI);
                float fl = sigmoidf_(acc[m][1] + bF);
                float fr = sigmoidf_(acc[m][2] + bF);
                float og = sigmoidf_(acc[m][3] + bO);
                float uv = tanhf(acc[m][4] + bU);
                float lc = p.C[(long)sl[m] * HSTR + h];
                float rc = p.C[(long)sr[m] * HSTR + h];
                float c  = ig * uv + fl * lc + fr * rc;
                float hh = og * tanhf(c);
                long node = node0 + m;
                p.H[node * HSTR + h] = hh;
                p.C[node * HSTR + h] = c;
            }
        }
        __syncthreads();
    }
}

__global__ __launch_bounds__(BLK) void fused(P p)
{
    __shared__ __align__(16) float Xs[EMB * 8];   // 9.6 KB
    __shared__ float red[BLK];
    __shared__ float bys[8];
    __shared__ int sl[8], sr[8];
    cg::grid_group grid = cg::this_grid();
    const int gtid = blockIdx.x * BLK + threadIdx.x;
    const int nthr = gridDim.x * BLK;

    // ---- phase 0: weight transpose/interleave ----
    for (int idx = gtid; idx < EMB * WCOLS3; idx += nthr) {
        int k = idx / WCOLS3, j = idx - k * WCOLS3;
        int h = j >> 2, g = j & 3;
        float v = 0.f;
        if (g < 3) {
            const float* W = (g == 0) ? p.Wi : (g == 1) ? p.Wo : p.Wu;
            v = W[h * EMB + k];
        }
        p.Wt3[idx] = v;
    }
    for (int idx = gtid; idx < EMB * UCOLS3; idx += nthr) {
        int k = idx / UCOLS3, j = idx - k * UCOLS3;
        int h = j >> 3, g = j & 7;
        float v = 0.f;
        if (g < 5) {
            bool L = (k < HID);
            int kk = L ? k : k - HID;
            const float* U =
                (g == 0) ? (L ? p.U0i : p.U1i) :
                (g == 1) ? (L ? p.U00f : p.U01f) :
                (g == 2) ? (L ? p.U10f : p.U11f) :
                (g == 3) ? (L ? p.U0o : p.U1o) :
                           (L ? p.U0u : p.U1u);
            v = U[h * HID + kk];
        }
        p.Ut3[idx] = v;
    }
    grid.sync();

    // ---- phase 1: leaves ----
    for (int t = blockIdx.x; t < NLEAF / 8; t += gridDim.x)
        leaf_tile(p, t, Xs, sl);
    grid.sync();

    // ---- phase 2: internal levels ----
    level_pass<8,1>(p, 11, Xs, sl, sr); grid.sync();
    level_pass<4,1>(p, 10, Xs, sl, sr); grid.sync();
    level_pass<4,2>(p,  9, Xs, sl, sr); grid.sync();
    level_pass<2,2>(p,  8, Xs, sl, sr); grid.sync();
    level_pass<2,4>(p,  7, Xs, sl, sr); grid.sync();
    level_pass<1,4>(p,  6, Xs, sl, sr); grid.sync();
    level_pass<1,8>(p,  5, Xs, sl, sr); grid.sync();
    level_pass<1,8>(p,  4, Xs, sl, sr); grid.sync();
    level_pass<1,8>(p,  3, Xs, sl, sr); grid.sync();
    level_pass<1,8>(p,  2, Xs, sl, sr); grid.sync();
    level_pass<1,8>(p,  1, Xs, sl, sr); grid.sync();
    level_pass<1,8>(p,  0, Xs, sl, sr); grid.sync();

    // ---- phase 3: loss ----
    float* Wys = Xs;  // 5*152 floats
    for (int i = threadIdx.x; i < NOUT * HSTR; i += BLK) {
        int g = i / HSTR, k = i - g * HSTR;
        Wys[i] = (k < HID) ? p.Why[g * HID + k] : 0.f;
    }
    if (threadIdx.x < NOUT) bys[threadIdx.x] = p.by[threadIdx.x];
    __syncthreads();

    float local = 0.f;
    for (int n = gtid; n < NNODES; n += nthr) {
        const float* hr = p.H + (long)n * HSTR;
        float l0 = bys[0], l1 = bys[1], l2 = bys[2], l3 = bys[3], l4 = bys[4];
        for (int k = 0; k < 148; k += 4) {
            float4 hv = *(const float4*)(hr + k);
            float4 w0 = *(const float4*)&Wys[0 * HSTR + k];
            float4 w1 = *(const float4*)&Wys[1 * HSTR + k];
            float4 w2 = *(const float4*)&Wys[2 * HSTR + k];
            float4 w3 = *(const float4*)&Wys[3 * HSTR + k];
            float4 w4 = *(const float4*)&Wys[4 * HSTR + k];
            l0 += hv.x*w0.x + hv.y*w0.y + hv.z*w0.z + hv.w*w0.w;
            l1 += hv.x*w1.x + hv.y*w1.y + hv.z*w1.z + hv.w*w1.w;
            l2 += hv.x*w2.x + hv.y*w2.y + hv.z*w2.z + hv.w*w2.w;
            l3 += hv.x*w3.x + hv.y*w3.y + hv.z*w3.z + hv.w*w3.w;
            l4 += hv.x*w4.x + hv.y*w4.y + hv.z*w4.z + hv.w*w4.w;
        }
        for (int k = 148; k < HID; ++k) {
            float hv = hr[k];
            l0 += hv * Wys[0*HSTR+k]; l1 += hv * Wys[1*HSTR+k]; l2 += hv * Wys[2*HSTR+k];
            l3 += hv * Wys[3*HSTR+k]; l4 += hv * Wys[4*HSTR+k];
        }
        float mx = fmaxf(fmaxf(fmaxf(l0, l1), fmaxf(l2, l3)), l4);
        float se = __expf(l0-mx) + __expf(l1-mx) + __expf(l2-mx) + __expf(l3-mx) + __expf(l4-mx);
        float lse = mx + __logf(se);
        int sc = p.scores[n];
        float lsc = (sc == 0) ? l0 : (sc == 1) ? l1 : (sc == 2) ? l2 : (sc == 3) ? l3 : l4;
        local += lse - lsc;
    }
    red[threadIdx.x] = local;
    __syncthreads();
    for (int st = 96; st >= 6; st >>= 1) {
        if (threadIdx.x < st) red[threadIdx.x] += red[threadIdx.x + st];
        __syncthreads();
    }
    if (threadIdx.x == 0)
        p.partials[blockIdx.x] = red[0]+red[1]+red[2]+red[3]+red[4]+red[5];
    grid.sync();

    if (blockIdx.x == 0) {
        float acc2 = 0.f;
        for (int i = threadIdx.x; i < gridDim.x; i += BLK) acc2 += p.partials[i];
        red[threadIdx.x] = acc2;
        __syncthreads();
        for (int st = 96; st >= 6; st >>= 1) {
            if (threadIdx.x < st) red[threadIdx.x] += red[threadIdx.x + st];
            __syncthreads();
        }
        if (threadIdx.x == 0)
            p.out[0] = red[0]+red[1]+red[2]+red[3]+red[4]+red[5];
    }
}

extern "C" void kernel_launch(void* const* d_in, const int* in_sizes, int n_in,
                              void* d_out, int out_size, void* d_ws, size_t ws_size,
                              hipStream_t stream)
{
    P p;
    p.Wi   = (const float*)d_in[0];
    p.bi   = (const float*)d_in[1];
    p.Wo   = (const float*)d_in[2];
    p.bo   = (const float*)d_in[3];
    p.Wu   = (const float*)d_in[4];
    p.bu   = (const float*)d_in[5];
    p.U0i  = (const float*)d_in[6];
    p.U1i  = (const float*)d_in[7];
    p.bbi  = (const float*)d_in[8];
    p.U00f = (const float*)d_in[9];
    p.U01f = (const float*)d_in[10];
    p.U10f = (const float*)d_in[11];
    p.U11f = (const float*)d_in[12];
    p.bbf  = (const float*)d_in[13];
    p.U0o  = (const float*)d_in[14];
    p.U1o  = (const float*)d_in[15];
    p.bbo  = (const float*)d_in[16];
    p.U0u  = (const float*)d_in[17];
    p.U1u  = (const float*)d_in[18];
    p.bbu  = (const float*)d_in[19];
    p.Why  = (const float*)d_in[20];
    p.by   = (const float*)d_in[21];
    p.emb  = (const float*)d_in[22];
    p.scores = (const int*)d_in[23];
    p.words  = (const int*)d_in[24];
    p.lchs   = (const int*)d_in[25];
    p.rchs   = (const int*)d_in[26];

    float* ws = (float*)d_ws;
    p.Wt3 = ws;                                   // 300*600  = 180000
    p.Ut3 = p.Wt3 + EMB * WCOLS3;                 // 300*1200 = 360000
    p.H   = p.Ut3 + EMB * UCOLS3;                 // 8191*152
    p.C   = p.H + (long)NNODES * HSTR;            // 8191*152
    p.partials = p.C + (long)NNODES * HSTR;       // MAXG
    p.out = (float*)d_out;

    int maxB = 0;
    hipOccupancyMaxActiveBlocksPerMultiprocessor(&maxB, fused, BLK, 0);
    if (maxB < 1) maxB = 1;
    int G = maxB * 256;
    if (G > MAXG) G = MAXG;

    void* kargs[] = { (void*)&p };
    hipLaunchCooperativeKernel((void*)fused, dim3(G), dim3(BLK), kargs, 0, stream);
}

// Round 4
// 537.393 us; speedup vs baseline: 2.5797x; 2.5797x over previous
//
#include <hip/hip_runtime.h>
#include <math.h>

#define HID 150
#define EMB 300
#define NNODES 8191
#define LEAF_START 4095
#define HSTR 152
#define UC 768            // Ut2 padded cols (750 used)
#define WC 456            // Wt2 padded cols (450 used)
#define BLK 768
#define NTILES 1352       // 512 leaf + 840 internal sub-tiles

// per-level tables, index = level d (0=root .. 11); leaves are level 12, special-cased
__device__ __constant__ int subOff_[12] = {1348,1344,1340,1336,1328,1312,1280,1216,1152,1024,768,512};
__device__ __constant__ int subT_[12]   = {4,4,4,4,8,16,32,64,64,128,256,256};
__device__ __constant__ int cntOff_[12] = {1025,1024,1023,1022,1020,1016,1008,992,960,896,768,512};
__device__ __constant__ int hs_[12]     = {4,4,4,4,4,4,4,4,2,2,2,1};

struct P {
    const float *Ut2, *Wt2, *ub, *wb, *Why, *by, *emb;
    const int *words, *lchs, *rchs, *scores;
    float *H, *C, *lossAcc, *out;
    int *cnt, *done;
};

struct Q {
    const float *Wi,*bi,*Wo,*bo,*Wu,*bu;
    const float *U0i,*U1i,*bbi,*U00f,*U01f,*U10f,*U11f,*bbf,*U0o,*U1o,*bbo,*U0u,*U1u,*bbu;
    float *Ut2,*Wt2,*ub,*wb;
    int *zeroI;
};

__device__ __forceinline__ float sigf(float x){ return 1.0f/(1.0f+__expf(-x)); }
__device__ __forceinline__ float aloadf(const float* p){ return __hip_atomic_load(p, __ATOMIC_RELAXED, __HIP_MEMORY_SCOPE_AGENT); }
__device__ __forceinline__ void astoref(float* p, float v){ __hip_atomic_store(p, v, __ATOMIC_RELAXED, __HIP_MEMORY_SCOPE_AGENT); }
__device__ __forceinline__ int aloadi(const int* p){ return __hip_atomic_load(p, __ATOMIC_RELAXED, __HIP_MEMORY_SCOPE_AGENT); }

// ---------------- prep: transposed/padded weights + fused biases + zero flags ----------------
__global__ __launch_bounds__(256) void prep(Q q)
{
    const long stride = (long)gridDim.x * 256;
    const long g0 = (long)blockIdx.x * 256 + threadIdx.x;
    for (long i = g0; i < 300L*UC; i += stride) {
        int k = (int)(i / UC), j = (int)(i - (long)k*UC); float v = 0.f;
        if (j < 750) {
            int g = j / 150, h = j - g*150; bool L = (k < HID); int kk = L ? k : k - HID;
            const float* U = (g==0) ? (L?q.U0i:q.U1i) : (g==1) ? (L?q.U00f:q.U01f) :
                             (g==2) ? (L?q.U10f:q.U11f) : (g==3) ? (L?q.U0o:q.U1o) : (L?q.U0u:q.U1u);
            v = U[h*HID + kk];
        }
        q.Ut2[i] = v;
    }
    for (long i = g0; i < 300L*WC; i += stride) {
        int k = (int)(i / WC), j = (int)(i - (long)k*WC); float v = 0.f;
        if (j < 450) {
            int g = j / 150, h = j - g*150;
            const float* W = (g==0) ? q.Wi : (g==1) ? q.Wo : q.Wu;
            v = W[h*EMB + k];
        }
        q.Wt2[i] = v;
    }
    for (long i = g0; i < UC; i += stride) {
        float v = 0.f;
        if (i < 750) { int g = (int)i/150, h = (int)i%150;
            const float* b = (g==0)?q.bbi:(g==1||g==2)?q.bbf:(g==3)?q.bbo:q.bbu; v = b[h]; }
        q.ub[i] = v;
    }
    for (long i = g0; i < WC; i += stride) {
        float v = 0.f;
        if (i < 450) { int g = (int)i/150, h = (int)i%150;
            const float* b = (g==0)?q.bi:(g==1)?q.bo:q.bu; v = b[h]; }
        q.wb[i] = v;
    }
    for (long i = g0; i < 1028; i += stride) q.zeroI[i] = 0;  // cnt[1026] + done + lossAcc
}

// ---------------- fused dataflow kernel ----------------
__global__ __launch_bounds__(BLK) void tree_fused(P p)
{
    __shared__ __align__(16) float Xs[2400];
    __shared__ __align__(16) float Gs[8*752];
    __shared__ float Ls[48];
    __shared__ float Lm[8];
    __shared__ int sl[8], sr[8];
    __shared__ int flagS;

    const int tid = threadIdx.x;

    for (int t = blockIdx.x; t < NTILES; t += gridDim.x) {
        if (t < 512) {
            // ================= leaf tile (8 leaves, 450 cols, hs=1) =================
            const int nt = t;
            const int nodeBase = LEAF_START + nt*8;
            if (tid < 8) sl[tid] = p.words[nodeBase + tid];
            __syncthreads();
            for (int idx = tid; idx < 2400; idx += BLK) {
                int m = idx / 300, k = idx - m*300;
                Xs[k*8 + m] = p.emb[(long)sl[m]*EMB + k];
            }
            __syncthreads();
            if (tid < 450) {
                float acc[8] = {0,0,0,0,0,0,0,0};
                const float* wp = p.Wt2 + tid;
#pragma unroll 4
                for (int k = 0; k < EMB; ++k) {
                    float w = wp[(long)k*WC];
                    float4 xa = *(const float4*)&Xs[k*8];
                    float4 xb = *(const float4*)&Xs[k*8 + 4];
                    acc[0]=fmaf(xa.x,w,acc[0]); acc[1]=fmaf(xa.y,w,acc[1]);
                    acc[2]=fmaf(xa.z,w,acc[2]); acc[3]=fmaf(xa.w,w,acc[3]);
                    acc[4]=fmaf(xb.x,w,acc[4]); acc[5]=fmaf(xb.y,w,acc[5]);
                    acc[6]=fmaf(xb.z,w,acc[6]); acc[7]=fmaf(xb.w,w,acc[7]);
                }
#pragma unroll
                for (int m = 0; m < 8; ++m) Gs[m*752 + tid] = acc[m];
            }
            __syncthreads();
            for (int idx = tid; idx < 1200; idx += BLK) {
                int m = idx / 150, h = idx - m*150;
                float ig = sigf(Gs[m*752 + h]        + p.wb[h]);
                float og = sigf(Gs[m*752 + 150 + h]  + p.wb[150+h]);
                float uv = tanhf(Gs[m*752 + 300 + h] + p.wb[300+h]);
                float c  = ig * uv;
                float hv = og * tanhf(c);
                long node = nodeBase + m;
                astoref(&p.H[node*HSTR + h], hv);
                astoref(&p.C[node*HSTR + h], c);
                Xs[m*150 + h] = hv;  // keep for inline loss
            }
            __syncthreads();
            if (tid == 0) atomicAdd(&p.cnt[nt], 1);   // publish: parents may start now
            // inline loss for the 8 leaves (H already in LDS)
            if (tid < 40) {
                int g = tid >> 3, m = tid & 7;
                float l = p.by[g];
                for (int h = 0; h < HID; ++h) l = fmaf(p.Why[g*HID + h], Xs[m*150 + h], l);
                Ls[g*8 + m] = l;
            }
            __syncthreads();
            if (tid < 8) {
                float l0=Ls[tid],l1=Ls[8+tid],l2=Ls[16+tid],l3=Ls[24+tid],l4=Ls[32+tid];
                float mx = fmaxf(fmaxf(fmaxf(l0,l1),fmaxf(l2,l3)),l4);
                float se = __expf(l0-mx)+__expf(l1-mx)+__expf(l2-mx)+__expf(l3-mx)+__expf(l4-mx);
                float lse = mx + __logf(se);
                int sc = p.scores[nodeBase + tid];
                float lsc = (sc==0)?l0:(sc==1)?l1:(sc==2)?l2:(sc==3)?l3:l4;
                Lm[tid] = lse - lsc;
            }
            __syncthreads();
            if (tid == 0) {
                float s = 0.f;
                for (int m = 0; m < 8; ++m) s += Lm[m];
                atomicAdd(p.lossAcc, s);
            }
            __syncthreads();
        } else {
            // ================= internal sub-tile =================
            int d;
            for (d = 11; d >= 1; --d) if (t < subOff_[d] + subT_[d]) break;
            const int idx2 = t - subOff_[d];
            const int hs = hs_[d];
            const int nt = idx2 / hs, hsi = idx2 - nt*hs;
            const int count = 1 << d;
            const int NB = count < 8 ? count : 8;
            const int nodeBase = (count - 1) + nt*NB;

            // dependencies: child node-tile counters
            int cbase, nchild, needHs;
            if (d == 11) { cbase = 2*nt; nchild = 2; needHs = 1; }
            else {
                int dc = d + 1, cc = 1 << dc;
                int NBc = cc < 8 ? cc : 8;
                cbase = cntOff_[dc] + (2*nt*NB)/NBc;
                nchild = (2*NB)/NBc; if (nchild < 1) nchild = 1;
                needHs = hs_[dc];
            }
            if (tid < 8) {
                int mm = tid < NB ? tid : NB-1;
                sl[tid] = p.lchs[nodeBase + mm];
                sr[tid] = p.rchs[nodeBase + mm];
            }
            if (tid < nchild)
                while (aloadi(&p.cnt[cbase + tid]) < needHs) __builtin_amdgcn_s_sleep(1);
            __syncthreads();

            // stage x = [lh || rh] for 8 (clamped) nodes, from LLC
            for (int idx = tid; idx < 2400; idx += BLK) {
                int m = idx / 300, k = idx - m*300;
                int row = (k < HID) ? sl[m] : sr[m];
                int kk  = (k < HID) ? k : k - HID;
                Xs[k*8 + m] = aloadf(&p.H[(long)row*HSTR + kk]);
            }
            __syncthreads();

            const int hbeg = (hsi*HID)/hs, hend = ((hsi+1)*HID)/hs;
            const int hlen = hend - hbeg;
            const int ncols = 5 * hlen;
            if (tid < ncols) {
                float acc[8] = {0,0,0,0,0,0,0,0};
                int g = tid / hlen, dh = tid - g*hlen;
                const float* wp = p.Ut2 + (g*HID + hbeg + dh);
#pragma unroll 4
                for (int k = 0; k < EMB; ++k) {
                    float w = wp[(long)k*UC];
                    float4 xa = *(const float4*)&Xs[k*8];
                    float4 xb = *(const float4*)&Xs[k*8 + 4];
                    acc[0]=fmaf(xa.x,w,acc[0]); acc[1]=fmaf(xa.y,w,acc[1]);
                    acc[2]=fmaf(xa.z,w,acc[2]); acc[3]=fmaf(xa.w,w,acc[3]);
                    acc[4]=fmaf(xb.x,w,acc[4]); acc[5]=fmaf(xb.y,w,acc[5]);
                    acc[6]=fmaf(xb.z,w,acc[6]); acc[7]=fmaf(xb.w,w,acc[7]);
                }
#pragma unroll
                for (int m = 0; m < 8; ++m) Gs[m*752 + tid] = acc[m];
            }
            __syncthreads();

            const int npairs = NB * hlen;
            for (int idx = tid; idx < npairs; idx += BLK) {
                int m = idx / hlen, dh2 = idx - m*hlen;
                int hh = hbeg + dh2;
                float ig = sigf (Gs[m*752 + dh2]          + p.ub[hh]);
                float fl = sigf (Gs[m*752 + hlen + dh2]   + p.ub[150+hh]);
                float fr = sigf (Gs[m*752 + 2*hlen + dh2] + p.ub[300+hh]);
                float og = sigf (Gs[m*752 + 3*hlen + dh2] + p.ub[450+hh]);
                float uv = tanhf(Gs[m*752 + 4*hlen + dh2] + p.ub[600+hh]);
                float lc = aloadf(&p.C[(long)sl[m]*HSTR + hh]);
                float rc = aloadf(&p.C[(long)sr[m]*HSTR + hh]);
                float c  = ig*uv + fl*lc + fr*rc;
                float hv = og * tanhf(c);
                long node = nodeBase + m;
                astoref(&p.H[node*HSTR + hh], hv);
                astoref(&p.C[node*HSTR + hh], c);
            }
            __syncthreads();
            if (tid == 0) {
                int old = atomicAdd(&p.cnt[cntOff_[d] + nt], 1);
                flagS = (old == hs - 1);   // last completer does the node-tile loss
            }
            __syncthreads();
            if (flagS) {
                for (int idx = tid; idx < NB*HID; idx += BLK) {
                    int m = idx / HID, hh = idx - m*HID;
                    Xs[m*HID + hh] = aloadf(&p.H[(long)(nodeBase+m)*HSTR + hh]);
                }
                __syncthreads();
                if (tid < 5*NB) {
                    int g = tid / NB, m = tid - g*NB;
                    float l = p.by[g];
                    for (int h = 0; h < HID; ++h) l = fmaf(p.Why[g*HID + h], Xs[m*150 + h], l);
                    Ls[g*8 + m] = l;
                }
                __syncthreads();
                if (tid < NB) {
                    float l0=Ls[tid],l1=Ls[8+tid],l2=Ls[16+tid],l3=Ls[24+tid],l4=Ls[32+tid];
                    float mx = fmaxf(fmaxf(fmaxf(l0,l1),fmaxf(l2,l3)),l4);
                    float se = __expf(l0-mx)+__expf(l1-mx)+__expf(l2-mx)+__expf(l3-mx)+__expf(l4-mx);
                    float lse = mx + __logf(se);
                    int sc = p.scores[nodeBase + tid];
                    float lsc = (sc==0)?l0:(sc==1)?l1:(sc==2)?l2:(sc==3)?l3:l4;
                    Lm[tid] = lse - lsc;
                }
                __syncthreads();
                if (tid == 0) {
                    float s = 0.f;
                    for (int m = 0; m < NB; ++m) s += Lm[m];
                    atomicAdd(p.lossAcc, s);
                }
            }
            __syncthreads();
        }
    }

    // block done; last block publishes the loss
    __syncthreads();
    if (tid == 0) {
        __threadfence();   // order lossAcc adds before done increment
        int old = atomicAdd(p.done, 1);
        if (old == (int)gridDim.x - 1) p.out[0] = aloadf(p.lossAcc);
    }
}

extern "C" void kernel_launch(void* const* d_in, const int* in_sizes, int n_in,
                              void* d_out, int out_size, void* d_ws, size_t ws_size,
                              hipStream_t stream)
{
    float* ws = (float*)d_ws;
    float* Ut2 = ws;                      // 300*768 = 230400
    float* Wt2 = Ut2 + 300*UC;            // 300*456 = 136800 -> 367200
    float* ub  = Wt2 + 300*WC;            // 768 -> 367968
    float* wb  = ub + UC;                 // 456 -> 368424
    float* H   = wb + WC;                 // 8191*152 -> +1245032
    float* C   = H + (long)NNODES*HSTR;
    float* tail = C + (long)NNODES*HSTR;  // cnt(1026 int) + done(int) + lossAcc(float)
    int*   cnt = (int*)tail;
    int*   done = cnt + 1026;
    float* lossAcc = (float*)(cnt + 1027);

    Q q;
    q.Wi  = (const float*)d_in[0];  q.bi  = (const float*)d_in[1];
    q.Wo  = (const float*)d_in[2];  q.bo  = (const float*)d_in[3];
    q.Wu  = (const float*)d_in[4];  q.bu  = (const float*)d_in[5];
    q.U0i = (const float*)d_in[6];  q.U1i = (const float*)d_in[7];
    q.bbi = (const float*)d_in[8];
    q.U00f= (const float*)d_in[9];  q.U01f= (const float*)d_in[10];
    q.U10f= (const float*)d_in[11]; q.U11f= (const float*)d_in[12];
    q.bbf = (const float*)d_in[13];
    q.U0o = (const float*)d_in[14]; q.U1o = (const float*)d_in[15];
    q.bbo = (const float*)d_in[16];
    q.U0u = (const float*)d_in[17]; q.U1u = (const float*)d_in[18];
    q.bbu = (const float*)d_in[19];
    q.Ut2 = Ut2; q.Wt2 = Wt2; q.ub = ub; q.wb = wb; q.zeroI = cnt;

    P p;
    p.Ut2 = Ut2; p.Wt2 = Wt2; p.ub = ub; p.wb = wb;
    p.Why = (const float*)d_in[20]; p.by = (const float*)d_in[21];
    p.emb = (const float*)d_in[22];
    p.scores = (const int*)d_in[23]; p.words = (const int*)d_in[24];
    p.lchs = (const int*)d_in[25];   p.rchs = (const int*)d_in[26];
    p.H = H; p.C = C; p.lossAcc = lossAcc; p.out = (float*)d_out;
    p.cnt = cnt; p.done = done;

    hipLaunchKernelGGL(prep, dim3(512), dim3(256), 0, stream, q);

    int maxB = 0;
    hipOccupancyMaxActiveBlocksPerMultiprocessor(&maxB, tree_fused, BLK, 0);
    int G = maxB * 256;
    if (G > 512) G = 512;
    if (G < 1) G = 256;

    void* kargs[] = { (void*)&p };
    hipLaunchCooperativeKernel((void*)tree_fused, dim3(G), dim3(BLK), kargs, 0, stream);
}

// Round 5
// 535.957 us; speedup vs baseline: 2.5866x; 1.0027x over previous
//
#include <hip/hip_runtime.h>
#include <math.h>

#define HID 150
#define EMB 300
#define NNODES 8191
#define LEAF_START 4095
#define HSTR 152
#define UC 768            // Ut2 padded cols (750 used)
#define WC 456            // Wt2 padded cols (450 used)
#define BLK 768
#define NTILES 1304       // 512 leaf + 792 internal sub-tiles

// per-level tables, index = level d (0=root .. 11); leaves special-cased
// d11: c4 path hs=1; d10..d6: hs=2,ks=2; d5..d0: hs=4,ks=4
__device__ __constant__ int subOff_[12] = {1300,1296,1292,1288,1280,1264,1248,1216,1152,1024,768,512};
__device__ __constant__ int subT_[12]   = {4,4,4,4,8,16,16,32,64,128,256,256};
__device__ __constant__ int cntOff_[12] = {1025,1024,1023,1022,1020,1016,1008,992,960,896,768,512};
__device__ __constant__ int hs_[12]     = {4,4,4,4,4,4,2,2,2,2,2,1};

struct P {
    const float *Ut2, *Wt2, *ub, *wb, *Why, *by, *emb;
    const int *words, *lchs, *rchs, *scores;
    float *H, *C, *lossAcc, *out;
    int *cnt, *done;
};

struct Q {
    const float *Wi,*bi,*Wo,*bo,*Wu,*bu;
    const float *U0i,*U1i,*bbi,*U00f,*U01f,*U10f,*U11f,*bbf,*U0o,*U1o,*bbo,*U0u,*U1u,*bbu;
    float *Ut2,*Wt2,*ub,*wb;
    int *zeroI;
};

__device__ __forceinline__ float sigf(float x){ return 1.0f/(1.0f+__expf(-x)); }
__device__ __forceinline__ float aloadf(const float* p){ return __hip_atomic_load(p, __ATOMIC_RELAXED, __HIP_MEMORY_SCOPE_AGENT); }
__device__ __forceinline__ void astoref(float* p, float v){ __hip_atomic_store(p, v, __ATOMIC_RELAXED, __HIP_MEMORY_SCOPE_AGENT); }
__device__ __forceinline__ int aloadi(const int* p){ return __hip_atomic_load(p, __ATOMIC_RELAXED, __HIP_MEMORY_SCOPE_AGENT); }

// ---------------- prep: transposed/padded weights + fused biases + zero flags ----------------
__global__ __launch_bounds__(256) void prep(Q q)
{
    const long stride = (long)gridDim.x * 256;
    const long g0 = (long)blockIdx.x * 256 + threadIdx.x;
    for (long i = g0; i < 300L*UC; i += stride) {
        int k = (int)(i / UC), j = (int)(i - (long)k*UC); float v = 0.f;
        if (j < 750) {
            int g = j / 150, h = j - g*150; bool L = (k < HID); int kk = L ? k : k - HID;
            const float* U = (g==0) ? (L?q.U0i:q.U1i) : (g==1) ? (L?q.U00f:q.U01f) :
                             (g==2) ? (L?q.U10f:q.U11f) : (g==3) ? (L?q.U0o:q.U1o) : (L?q.U0u:q.U1u);
            v = U[h*HID + kk];
        }
        q.Ut2[i] = v;
    }
    for (long i = g0; i < 300L*WC; i += stride) {
        int k = (int)(i / WC), j = (int)(i - (long)k*WC); float v = 0.f;
        if (j < 450) {
            int g = j / 150, h = j - g*150;
            const float* W = (g==0) ? q.Wi : (g==1) ? q.Wo : q.Wu;
            v = W[h*EMB + k];
        }
        q.Wt2[i] = v;
    }
    for (long i = g0; i < UC; i += stride) {
        float v = 0.f;
        if (i < 750) { int g = (int)i/150, h = (int)i%150;
            const float* b = (g==0)?q.bbi:(g==1||g==2)?q.bbf:(g==3)?q.bbo:q.bbu; v = b[h]; }
        q.ub[i] = v;
    }
    for (long i = g0; i < WC; i += stride) {
        float v = 0.f;
        if (i < 450) { int g = (int)i/150, h = (int)i%150;
            const float* b = (g==0)?q.bi:(g==1)?q.bo:q.bu; v = b[h]; }
        q.wb[i] = v;
    }
    for (long i = g0; i < 1028; i += stride) q.zeroI[i] = 0;  // cnt[1026] + done + lossAcc
}

// ---------------- fused dataflow kernel ----------------
__global__ __launch_bounds__(BLK) void tree_fused(P p)
{
    __shared__ __align__(16) float Xs[2400];
    __shared__ __align__(16) float Gs[6144];
    __shared__ float Ls[48];
    __shared__ float Lm[8];
    __shared__ int sl[8], sr[8];
    __shared__ int flagS;

    const int tid = threadIdx.x;

    for (int t = blockIdx.x; t < NTILES; t += gridDim.x) {
        if (t < 512) {
            // ================= leaf tile (8 leaves, c=4) =================
            const int nt = t;
            const int nodeBase = LEAF_START + nt*8;
            if (tid < 8) sl[tid] = p.words[nodeBase + tid];
            __syncthreads();
            for (int idx = tid; idx < 2400; idx += BLK) {
                int m = idx / 300, k = idx - m*300;
                Xs[k*8 + m] = p.emb[(long)sl[m]*EMB + k];
            }
            __syncthreads();
            if (tid < 114) {
                float4 acc[8];
#pragma unroll
                for (int m = 0; m < 8; ++m) acc[m] = make_float4(0.f,0.f,0.f,0.f);
                const float* wp = p.Wt2 + tid*4;
#pragma unroll 2
                for (int k = 0; k < EMB; ++k) {
                    float4 w = *(const float4*)(wp + (long)k*WC);
                    float4 xa = *(const float4*)&Xs[k*8];
                    float4 xb = *(const float4*)&Xs[k*8 + 4];
                    float xv[8] = {xa.x,xa.y,xa.z,xa.w,xb.x,xb.y,xb.z,xb.w};
#pragma unroll
                    for (int m = 0; m < 8; ++m) {
                        acc[m].x = fmaf(xv[m], w.x, acc[m].x);
                        acc[m].y = fmaf(xv[m], w.y, acc[m].y);
                        acc[m].z = fmaf(xv[m], w.z, acc[m].z);
                        acc[m].w = fmaf(xv[m], w.w, acc[m].w);
                    }
                }
#pragma unroll
                for (int m = 0; m < 8; ++m)
                    *(float4*)&Gs[m*752 + tid*4] = acc[m];
            }
            __syncthreads();
            for (int idx = tid; idx < 1200; idx += BLK) {
                int m = idx / 150, h = idx - m*150;
                float ig = sigf(Gs[m*752 + h]        + p.wb[h]);
                float og = sigf(Gs[m*752 + 150 + h]  + p.wb[150+h]);
                float uv = tanhf(Gs[m*752 + 300 + h] + p.wb[300+h]);
                float c  = ig * uv;
                float hv = og * tanhf(c);
                long node = nodeBase + m;
                astoref(&p.H[node*HSTR + h], hv);
                astoref(&p.C[node*HSTR + h], c);
                Xs[m*150 + h] = hv;  // keep for inline loss
            }
            __syncthreads();
            if (tid == 0) atomicAdd(&p.cnt[nt], 1);   // publish
            if (tid < 40) {
                int g = tid >> 3, m = tid & 7;
                float l = p.by[g];
                for (int h = 0; h < HID; ++h) l = fmaf(p.Why[g*HID + h], Xs[m*150 + h], l);
                Ls[g*8 + m] = l;
            }
            __syncthreads();
            if (tid < 8) {
                float l0=Ls[tid],l1=Ls[8+tid],l2=Ls[16+tid],l3=Ls[24+tid],l4=Ls[32+tid];
                float mx = fmaxf(fmaxf(fmaxf(l0,l1),fmaxf(l2,l3)),l4);
                float se = __expf(l0-mx)+__expf(l1-mx)+__expf(l2-mx)+__expf(l3-mx)+__expf(l4-mx);
                float lse = mx + __logf(se);
                int sc = p.scores[nodeBase + tid];
                float lsc = (sc==0)?l0:(sc==1)?l1:(sc==2)?l2:(sc==3)?l3:l4;
                Lm[tid] = lse - lsc;
            }
            __syncthreads();
            if (tid == 0) {
                float s = 0.f;
                for (int m = 0; m < 8; ++m) s += Lm[m];
                atomicAdd(p.lossAcc, s);
            }
            __syncthreads();
        } else {
            // ================= internal sub-tile =================
            int d;
            for (d = 11; d >= 0; --d) if (t < subOff_[d] + subT_[d]) break;
            const int idx2 = t - subOff_[d];
            const int hs = hs_[d];
            const int nt = idx2 / hs, hsi = idx2 - nt*hs;
            const int count = 1 << d;
            const int NB = count < 8 ? count : 8;
            const int nodeBase = (count - 1) + nt*NB;

            int cbase, nchild, needHs;
            if (d == 11) { cbase = 2*nt; nchild = 2; needHs = 1; }
            else {
                int dc = d + 1, cc = 1 << dc;
                int NBc = cc < 8 ? cc : 8;
                cbase = cntOff_[dc] + (2*nt*NB)/NBc;
                nchild = (2*NB)/NBc; if (nchild < 1) nchild = 1;
                needHs = hs_[dc];
            }
            if (tid < 8) {
                int mm = tid < NB ? tid : NB-1;
                sl[tid] = p.lchs[nodeBase + mm];
                sr[tid] = p.rchs[nodeBase + mm];
            }
            if (tid < nchild)
                while (aloadi(&p.cnt[cbase + tid]) < needHs) __builtin_amdgcn_s_sleep(1);
            __syncthreads();

            for (int idx = tid; idx < 2400; idx += BLK) {
                int m = idx / 300, k = idx - m*300;
                int row = (k < HID) ? sl[m] : sr[m];
                int kk  = (k < HID) ? k : k - HID;
                Xs[k*8 + m] = aloadf(&p.H[(long)row*HSTR + kk]);
            }
            __syncthreads();

            if (d == 11) {
                // c=4 heavy path, full 750 cols, full K
                if (tid < 188) {
                    float4 acc[8];
#pragma unroll
                    for (int m = 0; m < 8; ++m) acc[m] = make_float4(0.f,0.f,0.f,0.f);
                    const float* wp = p.Ut2 + tid*4;
#pragma unroll 2
                    for (int k = 0; k < EMB; ++k) {
                        float4 w = *(const float4*)(wp + (long)k*UC);
                        float4 xa = *(const float4*)&Xs[k*8];
                        float4 xb = *(const float4*)&Xs[k*8 + 4];
                        float xv[8] = {xa.x,xa.y,xa.z,xa.w,xb.x,xb.y,xb.z,xb.w};
#pragma unroll
                        for (int m = 0; m < 8; ++m) {
                            acc[m].x = fmaf(xv[m], w.x, acc[m].x);
                            acc[m].y = fmaf(xv[m], w.y, acc[m].y);
                            acc[m].z = fmaf(xv[m], w.z, acc[m].z);
                            acc[m].w = fmaf(xv[m], w.w, acc[m].w);
                        }
                    }
#pragma unroll
                    for (int m = 0; m < 8; ++m)
                        *(float4*)&Gs[m*752 + tid*4] = acc[m];
                }
            } else if (d >= 6) {
                // hs=2, ks=2: 375 cols x 2 k-halves, kseg=150
                const int kh = tid / 384, cj = tid - kh*384;
                const int hbeg = hsi*75, hlen = 75;
                const int ncols = 5*hlen;      // 375
                if (kh < 2 && cj < ncols) {
                    int g = cj / hlen, dh = cj - g*hlen;
                    const float* wp = p.Ut2 + (g*HID + hbeg + dh);
                    float acc[8] = {0,0,0,0,0,0,0,0};
                    const int k0 = kh*150;
#pragma unroll 4
                    for (int k = k0; k < k0+150; ++k) {
                        float w = wp[(long)k*UC];
                        float4 xa = *(const float4*)&Xs[k*8];
                        float4 xb = *(const float4*)&Xs[k*8 + 4];
                        acc[0]=fmaf(xa.x,w,acc[0]); acc[1]=fmaf(xa.y,w,acc[1]);
                        acc[2]=fmaf(xa.z,w,acc[2]); acc[3]=fmaf(xa.w,w,acc[3]);
                        acc[4]=fmaf(xb.x,w,acc[4]); acc[5]=fmaf(xb.y,w,acc[5]);
                        acc[6]=fmaf(xb.z,w,acc[6]); acc[7]=fmaf(xb.w,w,acc[7]);
                    }
#pragma unroll
                    for (int m = 0; m < 8; ++m) Gs[(kh*8 + m)*384 + cj] = acc[m];
                }
            } else {
                // hs=4, ks=4: <=190 cols x 4 k-quarters, kseg=75
                const int kh = tid / 192, cj = tid - kh*192;
                const int hbeg = (hsi*HID)/4, hend = ((hsi+1)*HID)/4, hlen = hend - hbeg;
                const int ncols = 5*hlen;
                if (cj < ncols) {
                    int g = cj / hlen, dh = cj - g*hlen;
                    const float* wp = p.Ut2 + (g*HID + hbeg + dh);
                    float acc[8] = {0,0,0,0,0,0,0,0};
                    const int k0 = kh*75;
#pragma unroll 5
                    for (int k = k0; k < k0+75; ++k) {
                        float w = wp[(long)k*UC];
                        float4 xa = *(const float4*)&Xs[k*8];
                        float4 xb = *(const float4*)&Xs[k*8 + 4];
                        acc[0]=fmaf(xa.x,w,acc[0]); acc[1]=fmaf(xa.y,w,acc[1]);
                        acc[2]=fmaf(xa.z,w,acc[2]); acc[3]=fmaf(xa.w,w,acc[3]);
                        acc[4]=fmaf(xb.x,w,acc[4]); acc[5]=fmaf(xb.y,w,acc[5]);
                        acc[6]=fmaf(xb.z,w,acc[6]); acc[7]=fmaf(xb.w,w,acc[7]);
                    }
#pragma unroll
                    for (int m = 0; m < 8; ++m) Gs[(kh*8 + m)*192 + cj] = acc[m];
                }
            }
            __syncthreads();

            // ---- generic epilogue: sum k-partials, gates, store ----
            int hbeg2, hlen2, cpad2, ksn;
            if (d == 11)      { hbeg2 = 0;            hlen2 = 150;                          cpad2 = 752; ksn = 1; }
            else if (d >= 6)  { hbeg2 = hsi*75;       hlen2 = 75;                           cpad2 = 384; ksn = 2; }
            else              { hbeg2 = (hsi*HID)/4;  hlen2 = ((hsi+1)*HID)/4 - hbeg2;      cpad2 = 192; ksn = 4; }
            for (int idx = tid; idx < NB*hlen2; idx += BLK) {
                int m = idx / hlen2, dh2 = idx - m*hlen2;
                int hh = hbeg2 + dh2;
                float pre[5];
#pragma unroll
                for (int g = 0; g < 5; ++g) {
                    float s = 0.f;
                    for (int k2 = 0; k2 < ksn; ++k2)
                        s += Gs[(k2*8 + m)*cpad2 + g*hlen2 + dh2];
                    pre[g] = s;
                }
                float ig = sigf (pre[0] + p.ub[hh]);
                float fl = sigf (pre[1] + p.ub[150+hh]);
                float fr = sigf (pre[2] + p.ub[300+hh]);
                float og = sigf (pre[3] + p.ub[450+hh]);
                float uv = tanhf(pre[4] + p.ub[600+hh]);
                float lc = aloadf(&p.C[(long)sl[m]*HSTR + hh]);
                float rc = aloadf(&p.C[(long)sr[m]*HSTR + hh]);
                float c  = ig*uv + fl*lc + fr*rc;
                float hv = og * tanhf(c);
                long node = nodeBase + m;
                astoref(&p.H[node*HSTR + hh], hv);
                astoref(&p.C[node*HSTR + hh], c);
            }
            __syncthreads();
            if (tid == 0) {
                int old = atomicAdd(&p.cnt[cntOff_[d] + nt], 1);
                flagS = (old == hs - 1);   // last completer does the node-tile loss
            }
            __syncthreads();
            if (flagS) {
                for (int idx = tid; idx < NB*HID; idx += BLK) {
                    int m = idx / HID, hh = idx - m*HID;
                    Xs[m*HID + hh] = aloadf(&p.H[(long)(nodeBase+m)*HSTR + hh]);
                }
                __syncthreads();
                if (tid < 5*NB) {
                    int g = tid / NB, m = tid - g*NB;
                    float l = p.by[g];
                    for (int h = 0; h < HID; ++h) l = fmaf(p.Why[g*HID + h], Xs[m*150 + h], l);
                    Ls[g*8 + m] = l;
                }
                __syncthreads();
                if (tid < NB) {
                    float l0=Ls[tid],l1=Ls[8+tid],l2=Ls[16+tid],l3=Ls[24+tid],l4=Ls[32+tid];
                    float mx = fmaxf(fmaxf(fmaxf(l0,l1),fmaxf(l2,l3)),l4);
                    float se = __expf(l0-mx)+__expf(l1-mx)+__expf(l2-mx)+__expf(l3-mx)+__expf(l4-mx);
                    float lse = mx + __logf(se);
                    int sc = p.scores[nodeBase + tid];
                    float lsc = (sc==0)?l0:(sc==1)?l1:(sc==2)?l2:(sc==3)?l3:l4;
                    Lm[tid] = lse - lsc;
                }
                __syncthreads();
                if (tid == 0) {
                    float s = 0.f;
                    for (int m = 0; m < NB; ++m) s += Lm[m];
                    atomicAdd(p.lossAcc, s);
                }
            }
            __syncthreads();
        }
    }

    __syncthreads();
    if (tid == 0) {
        __threadfence();
        int old = atomicAdd(p.done, 1);
        if (old == (int)gridDim.x - 1) p.out[0] = aloadf(p.lossAcc);
    }
}

extern "C" void kernel_launch(void* const* d_in, const int* in_sizes, int n_in,
                              void* d_out, int out_size, void* d_ws, size_t ws_size,
                              hipStream_t stream)
{
    float* ws = (float*)d_ws;
    float* Ut2 = ws;                      // 300*768
    float* Wt2 = Ut2 + 300*UC;            // 300*456
    float* ub  = Wt2 + 300*WC;            // 768
    float* wb  = ub + UC;                 // 456
    float* H   = wb + WC;                 // 8191*152
    float* C   = H + (long)NNODES*HSTR;
    float* tail = C + (long)NNODES*HSTR;  // cnt(1026) + done + lossAcc
    int*   cnt = (int*)tail;
    int*   done = cnt + 1026;
    float* lossAcc = (float*)(cnt + 1027);

    Q q;
    q.Wi  = (const float*)d_in[0];  q.bi  = (const float*)d_in[1];
    q.Wo  = (const float*)d_in[2];  q.bo  = (const float*)d_in[3];
    q.Wu  = (const float*)d_in[4];  q.bu  = (const float*)d_in[5];
    q.U0i = (const float*)d_in[6];  q.U1i = (const float*)d_in[7];
    q.bbi = (const float*)d_in[8];
    q.U00f= (const float*)d_in[9];  q.U01f= (const float*)d_in[10];
    q.U10f= (const float*)d_in[11]; q.U11f= (const float*)d_in[12];
    q.bbf = (const float*)d_in[13];
    q.U0o = (const float*)d_in[14]; q.U1o = (const float*)d_in[15];
    q.bbo = (const float*)d_in[16];
    q.U0u = (const float*)d_in[17]; q.U1u = (const float*)d_in[18];
    q.bbu = (const float*)d_in[19];
    q.Ut2 = Ut2; q.Wt2 = Wt2; q.ub = ub; q.wb = wb; q.zeroI = cnt;

    P p;
    p.Ut2 = Ut2; p.Wt2 = Wt2; p.ub = ub; p.wb = wb;
    p.Why = (const float*)d_in[20]; p.by = (const float*)d_in[21];
    p.emb = (const float*)d_in[22];
    p.scores = (const int*)d_in[23]; p.words = (const int*)d_in[24];
    p.lchs = (const int*)d_in[25];   p.rchs = (const int*)d_in[26];
    p.H = H; p.C = C; p.lossAcc = lossAcc; p.out = (float*)d_out;
    p.cnt = cnt; p.done = done;

    hipLaunchKernelGGL(prep, dim3(512), dim3(256), 0, stream, q);

    int maxB = 0;
    hipOccupancyMaxActiveBlocksPerMultiprocessor(&maxB, tree_fused, BLK, 0);
    int G = maxB * 256;
    if (G > 512) G = 512;
    if (G < 1) G = 256;

    void* kargs[] = { (void*)&p };
    hipLaunchCooperativeKernel((void*)tree_fused, dim3(G), dim3(BLK), kargs, 0, stream);
}